// Round 17
// baseline (162.523 us; speedup 1.0000x reference)
//
#include <hip/hip_runtime.h>
#include <cstdint>

typedef __attribute__((ext_vector_type(8))) _Float16 f16x8;
typedef __attribute__((ext_vector_type(4))) float f32x4;

#define DEV static __device__ __forceinline__

DEV void gld_lds16(void* lds_base, const void* gsrc) {
  __builtin_amdgcn_global_load_lds(
      (const __attribute__((address_space(1))) unsigned int*)gsrc,
      (__attribute__((address_space(3))) unsigned int*)lds_base,
      16, 0, 0);
}
DEV unsigned short f2h(float f) {
  _Float16 h = (_Float16)f;
  return __builtin_bit_cast(unsigned short, h);
}
DEV unsigned pk2h(float a, float b) {
  auto h2 = __builtin_amdgcn_cvt_pkrtz(a, b);
  return __builtin_bit_cast(unsigned, h2);
}
DEV float v_exp2(float x) { float r; asm("v_exp_f32 %0, %1" : "=v"(r) : "v"(x)); return r; }
DEV float v_rcp(float x) { float r; asm("v_rcp_f32 %0, %1" : "=v"(r) : "v"(x)); return r; }

// ---------------- geometry ----------------
// B=4, C=256, H=W=64, N=4096, heads=2, hd=128
// ws layout (bytes):
//   Xpad [4][74][74][256] f16 : 0        .. 11214848
//   Wq [3][3][256][256] f16   : 11214848 .. 12394496
//   Wk [256][256] f16         : 12394496 .. 12525568
//   Wv [256][256] f16         : 12525568 .. 12656640
//   Q  [8][4096][128] f16     : 12656640 .. 21045248   (pre-scaled by log2e/sqrt(128))
//   K  [8][4096][128] f16     : 21045248 .. 29433856
//   V  [8][128][4096] f16     : 29433856 .. 37822464   (m-permuted per 64-block: s=[m5,m3,m2,m4,m1,m0])

// ---------- prep: x -> Xpad (f16, pixel-major, halo 5) + halo zeroing + weights -> f16 ----------
__global__ __launch_bounds__(256) void k_prep_x(
    const float* __restrict__ x, char* __restrict__ xpad,
    const float* __restrict__ qw, const float* __restrict__ kw, const float* __restrict__ vw,
    unsigned short* __restrict__ Wq, unsigned short* __restrict__ Wk, unsigned short* __restrict__ Wv) {
  __shared__ float xs[32 * 257];
  int h = blockIdx.x, b = blockIdx.y, t = threadIdx.x;
  // fused weight conversion (one gid per thread; 256 blocks x 256 threads cover 65536)
  int gid = (b * 64 + h) * 256 + t;
  const float* q9 = qw + (size_t)gid * 9;
#pragma unroll
  for (int tp = 0; tp < 9; tp++) Wq[tp * 65536 + gid] = f2h(q9[tp]);
  Wk[gid] = f2h(kw[gid]);
  Wv[gid] = f2h(vw[gid]);
  // halo zeroing (replaces the 11MB memset): disjoint from all data writes
  uint4 z = {0, 0, 0, 0};
  char* rowbase = xpad + ((size_t)(b * 74 + h + 5) * 74) * 512;
  for (int i = t; i < 320; i += 256) {              // col halo of this data row
    int col = i >> 5, off = (i & 31) * 16;
    int w = (col < 5) ? col : 64 + col;             // cols 0-4, 69-73
    *(uint4*)(rowbase + (size_t)w * 512 + off) = z;
  }
  if (h < 10) {                                     // full halo rows 0-4, 69-73
    int r = (h < 5) ? h : 64 + h;
    char* rb = xpad + ((size_t)(b * 74 + r) * 74) * 512;
    for (int i = t; i < 2368; i += 256) *(uint4*)(rb + (size_t)i * 16) = z;
  }
  const float* xb = x + (size_t)b * 1048576 + h * 64;
  for (int half = 0; half < 2; half++) {
    int w0 = half * 32;
    for (int kk = 0; kk < 32; kk++) {
      int flat = kk * 256 + t;       // ci*32 + w
      int ci = flat >> 5, w = flat & 31;
      xs[w * 257 + ci] = xb[ci * 4096 + w0 + w];
    }
    __syncthreads();
    for (int g = 0; g < 4; g++) {
      int w = g * 8 + (t >> 5);
      int cg = t & 31;               // 8-ci chunk
      float v0 = xs[w * 257 + cg * 8 + 0], v1 = xs[w * 257 + cg * 8 + 1];
      float v2 = xs[w * 257 + cg * 8 + 2], v3 = xs[w * 257 + cg * 8 + 3];
      float v4 = xs[w * 257 + cg * 8 + 4], v5 = xs[w * 257 + cg * 8 + 5];
      float v6 = xs[w * 257 + cg * 8 + 6], v7 = xs[w * 257 + cg * 8 + 7];
      uint4 pk;
      pk.x = pk2h(v0, v1);
      pk.y = pk2h(v2, v3);
      pk.z = pk2h(v4, v5);
      pk.w = pk2h(v6, v7);
      *(uint4*)(xpad + ((size_t)((b * 74 + h + 5) * 74) + w0 + w + 5) * 512 + cg * 16) = pk;
    }
    __syncthreads();
  }
}

// ---------- 1x1 convs: K[bh][m][d], V[bh][d][s(m)] ----------
// c-loop double-buffered: X/W ping-pong (64KB LDS), staging hidden under compute.
__global__ __launch_bounds__(256, 2) void k_conv_kv(
    const char* __restrict__ xpad, const unsigned short* __restrict__ Wk,
    const unsigned short* __restrict__ Wv, const float* __restrict__ kb,
    const float* __restrict__ vb, unsigned short* __restrict__ K, unsigned short* __restrict__ V) {
  __shared__ char sm[65536];   // buf0: X@0 W@16384 ; buf1: X@32768 W@49152
  int t = threadIdx.x, lane = t & 63, wid = t >> 6, q4 = lane >> 4, l15 = lane & 15;
  int px0 = blockIdx.x * 128;
  int b = px0 >> 12, nn = px0 & 4095;
  int h = blockIdx.y;          // co half / head
  int mode = blockIdx.z;       // 0: K (D[px][co]),  1: V (D[co][px])
  int co0 = h * 128;
  const char* Wsrc = (const char*)(mode ? Wv : Wk);
  int wm = wid & 1, wn = wid >> 1;

#define STAGE_KV(base_, c_)                                                       \
  {                                                                               \
    for (int ch = wid * 1024; ch < 16384; ch += 4096) {                           \
      int o = ch + lane * 16;                                                     \
      int r = o >> 7;                                                             \
      int n = nn + r, hh = n >> 6, ww2 = n & 63;                                  \
      int col = (o & 127) ^ ((r & 7) << 4);                                       \
      gld_lds16((base_) + ch,                                                     \
                xpad + ((size_t)((b * 74 + hh + 5) * 74) + ww2 + 5) * 512 + (c_)*128 + col); \
    }                                                                             \
    for (int ch = wid * 1024; ch < 16384; ch += 4096) {                           \
      int o = ch + lane * 16;                                                     \
      int r = o >> 7;                                                             \
      int col = (o & 127) ^ ((r & 7) << 4);                                       \
      gld_lds16((base_) + 16384 + ch, Wsrc + (co0 + r) * 512 + (c_)*128 + col);   \
    }                                                                             \
  }

  STAGE_KV(sm, 0);
  asm volatile("s_waitcnt vmcnt(0)" ::: "memory");
  __syncthreads();

  f32x4 acc[4][4] = {};
  for (int c = 0; c < 4; c++) {
    char* cb = sm + (c & 1) * 32768;
    if (c < 3) STAGE_KV(sm + ((c & 1) ^ 1) * 32768, c + 1);
    const char* Xs = cb;
    const char* Ws = cb + 16384;
    int xg = mode ? wn : wm;   // X-frag 64-row group
    int wg = mode ? wm : wn;   // W-frag 64-row group
#pragma unroll
    for (int kt = 0; kt < 2; kt++) {
      f16x8 xf[4], wf[4];
#pragma unroll
      for (int i = 0; i < 4; i++) {
        int rx = xg * 64 + i * 16 + l15;
        xf[i] = *(const f16x8*)(Xs + ((rx * 128 + kt * 64 + q4 * 16) ^ ((rx & 7) << 4)));
        int rw = wg * 64 + i * 16 + l15;
        wf[i] = *(const f16x8*)(Ws + ((rw * 128 + kt * 64 + q4 * 16) ^ ((rw & 7) << 4)));
      }
#pragma unroll
      for (int m = 0; m < 4; m++)
#pragma unroll
        for (int n = 0; n < 4; n++)
          acc[m][n] = mode ? __builtin_amdgcn_mfma_f32_16x16x32_f16(wf[m], xf[n], acc[m][n], 0, 0, 0)
                           : __builtin_amdgcn_mfma_f32_16x16x32_f16(xf[m], wf[n], acc[m][n], 0, 0, 0);
    }
    asm volatile("s_waitcnt vmcnt(0)" ::: "memory");
    __syncthreads();
  }
#undef STAGE_KV
  int bh = b * 2 + h;
  if (mode == 0) {
#pragma unroll
    for (int m = 0; m < 4; m++)
#pragma unroll
      for (int n = 0; n < 4; n++) {
        int dd = wn * 64 + n * 16 + l15;
        float bias = kb[co0 + dd];
#pragma unroll
        for (int j = 0; j < 4; j++) {
          int npix = nn + wm * 64 + m * 16 + q4 * 4 + j;
          K[(size_t)(bh * 4096 + npix) * 128 + dd] = f2h(acc[m][n][j] + bias);
        }
      }
  } else {
#pragma unroll
    for (int m = 0; m < 4; m++)
#pragma unroll
      for (int j = 0; j < 4; j++) {
        int cr = wm * 64 + m * 16 + q4 * 4 + j;
        float bias = vb[co0 + cr];
#pragma unroll
        for (int n = 0; n < 4; n++) {
          // m-permuted storage within each 64-block: m_local = n*16 + l15
          // -> s = (n>>1)*32 + (l15>>2)*8 + (n&1)*4 + (l15&3)
          int pc = nn + wn * 64 + (n >> 1) * 32 + (l15 >> 2) * 8 + (n & 1) * 4 + (l15 & 3);
          V[(size_t)(bh * 128 + cr) * 4096 + pc] = f2h(acc[m][n][j] + bias);
        }
      }
  }
}

// ---------- dilated 3x3 conv sum(SiLU) -> Q[bh][n][d] ----------
// 512-thread blocks (8 waves), 128 px (2 h-rows) per block, grid 256 (XCD-swizzled), 1 block/CU.
// Bs double-buffered at kw granularity AND As double-buffered per (kh,c).
__global__ __launch_bounds__(512, 2) void k_conv_q(
    const char* __restrict__ xpad, const unsigned short* __restrict__ Wq,
    const float* __restrict__ qb, unsigned short* __restrict__ Q) {
  extern __shared__ char sm[];
  int t = threadIdx.x, lane = t & 63, wid = t >> 6, q4 = lane >> 4, l15 = lane & 15;
  int fblk = blockIdx.x;
  int g = (fblk & 7) * 32 + (fblk >> 3);       // XCD x owns one (b,ch2) combo
  int h2 = g & 31, b = (g >> 5) & 3, ch2 = g >> 7;
  int h0 = h2 * 2;
  int co0 = ch2 * 128;
  int wn = wid & 1, wq = wid >> 1;
  int hr = wq >> 1, wloc = wq & 1;
  const int dil[3] = {1, 3, 5};
  const char* WqB = (const char*)Wq;
  f32x4 accd[3][2][4] = {};

#define STAGE_B(dstbuf, kh_, c_, kw_)                                             \
  {                                                                               \
    const char* src_ = WqB + (size_t)((kh_)*3 + (kw_)) * 131072 + co0 * 512 + (c_)*128; \
    char* dst_ = (dstbuf);                                                        \
    for (int ch = wid * 1024; ch < 16384; ch += 8192) {                           \
      int o = ch + lane * 16;                                                     \
      int r = o >> 7;                                                             \
      int col = (o & 127) ^ ((r & 7) << 4);                                       \
      gld_lds16(dst_ + ch, src_ + r * 512 + col);                                 \
    }                                                                             \
  }

#define STAGE_A_ROW(abase_, slot_, pr_, c_)                                       \
  {                                                                               \
    const char* src_ = xpad + ((size_t)(b * 74 + (pr_)) * 74) * 512 + (c_)*128;   \
    char* dst_ = (abase_) + (slot_)*9472;                                         \
    for (int ch = wid * 1024; ch < 9472; ch += 8192) {                            \
      int o = ch + lane * 16;                                                     \
      if (o < 9472) {                                                             \
        int r = o >> 7;                                                           \
        int col = (o & 127) ^ ((r & 7) << 4);                                     \
        gld_lds16(dst_ + ch, src_ + r * 512 + col);                               \
      }                                                                           \
    }                                                                             \
  }

#define STAGE_A(abase_, kh_, c_)                                                  \
  {                                                                               \
    if ((kh_) == 1) {                                                             \
      for (int s = 0; s < 2; s++) STAGE_A_ROW(abase_, s, h0 + s + 5, c_);         \
    } else {                                                                      \
      for (int di = 0; di < 3; di++)                                              \
        for (int s = 0; s < 2; s++)                                               \
          STAGE_A_ROW(abase_, di * 2 + s, h0 + s + ((kh_)-1) * dil[di] + 5, c_);  \
    }                                                                             \
  }

  // prologue
  STAGE_A(sm + 32768, 0, 0);
  STAGE_B(sm, 0, 0, 0);
  asm volatile("s_waitcnt vmcnt(0)" ::: "memory");
  __syncthreads();

  int curB = 0, curA = 0;
  for (int kh = 0; kh < 3; kh++) {
    for (int c = 0; c < 4; c++) {
      // next (kh,c) for the As prefetch
      int cn2 = c + 1, khn2 = kh;
      if (cn2 == 4) { cn2 = 0; khn2 = kh + 1; }
      for (int kw = 0; kw < 3; kw++) {
        // prefetch next unit's weights
        int kwn = kw + 1, cn = c, khn = kh;
        if (kwn == 3) { kwn = 0; cn = c + 1; if (cn == 4) { cn = 0; khn = kh + 1; } }
        char* Bnext = curB ? sm : sm + 16384;
        if (khn < 3) STAGE_B(Bnext, khn, cn, kwn);
        // prefetch next (kh,c)'s As during the kw==0 unit
        if (kw == 0 && khn2 < 3) STAGE_A(sm + 32768 + (curA ^ 1) * 56832, khn2, cn2);
        // compute unit (kh, c, kw)
        const char* Bc = curB ? sm + 16384 : sm;
        const char* Abase = sm + 32768 + curA * 56832;
        f16x8 bf[4][2];
#pragma unroll
        for (int n = 0; n < 4; n++)
#pragma unroll
          for (int kt = 0; kt < 2; kt++) {
            int rc = wn * 64 + n * 16 + l15;
            bf[n][kt] = *(const f16x8*)(Bc + ((rc * 128 + kt * 64 + q4 * 16) ^ ((rc & 7) << 4)));
          }
#pragma unroll
        for (int di = 0; di < 3; di++) {
          int dw = (kw - 1) * dil[di] + 5;
          const char* Ad = Abase + (kh == 1 ? hr : di * 2 + hr) * 9472;
          f16x8 af[2][2];
#pragma unroll
          for (int m = 0; m < 2; m++)
#pragma unroll
            for (int kt = 0; kt < 2; kt++) {
              int wp = wloc * 32 + m * 16 + l15 + dw;    // [0,73]
              af[m][kt] = *(const f16x8*)(Ad + ((wp * 128 + kt * 64 + q4 * 16) ^ ((wp & 7) << 4)));
            }
          __builtin_amdgcn_s_setprio(1);
#pragma unroll
          for (int m = 0; m < 2; m++)
#pragma unroll
            for (int n = 0; n < 4; n++)
#pragma unroll
              for (int kt = 0; kt < 2; kt++)
                accd[di][m][n] = __builtin_amdgcn_mfma_f32_16x16x32_f16(af[m][kt], bf[n][kt], accd[di][m][n], 0, 0, 0);
          __builtin_amdgcn_s_setprio(0);
        }
        asm volatile("s_waitcnt vmcnt(0)" ::: "memory");  // drain prefetches
        __syncthreads();
        curB ^= 1;
      }
      if (khn2 < 3) curA ^= 1;   // flip As at (kh,c) boundary when a prefetch was issued
    }
  }
#undef STAGE_A
#undef STAGE_A_ROW
#undef STAGE_B
  const float LOG2E = 1.4426950408889634f;
  const float QSCALE = 0.12751879523176862f;  // log2e / sqrt(128)
#pragma unroll
  for (int n = 0; n < 4; n++) {
    float bias = qb[co0 + wn * 64 + n * 16 + l15];
#pragma unroll
    for (int m = 0; m < 2; m++)
#pragma unroll
      for (int j = 0; j < 4; j++) {
        float s = 0.f;
#pragma unroll
        for (int di = 0; di < 3; di++) {
          float v = accd[di][m][n][j] + bias;
          s += v * v_rcp(1.0f + v_exp2(-v * LOG2E));     // SiLU
        }
        int w = wloc * 32 + m * 16 + q4 * 4 + j;
        int npix = (h0 + hr) * 64 + w;
        int dd = wn * 64 + n * 16 + l15;
        Q[((size_t)(b * 2 + ch2) * 4096 + npix) * 128 + dd] = f2h(s * QSCALE);
      }
  }
}

// ---------- flash attention, fused halves + per-group software barriers ----------
// grid 256 (XCD-swizzled), 512 threads, 1 block/CU. Two data-independent 4-wave groups
// (group = wid>>2) each process one KV half in their own 64KB LDS bank. Per-iteration sync
// is a GROUP-LOCAL monotonic-counter barrier (vmcnt drain + atomicAdd + spin) instead of
// __syncthreads, so the two groups drift in phase: one group's MFMA overlaps the other's
// softmax VALU/LDS. Full __syncthreads only around the final merge.
__global__ __launch_bounds__(512) void k_attn(
    const unsigned short* __restrict__ Q, const unsigned short* __restrict__ K,
    const unsigned short* __restrict__ V, float* __restrict__ out) {
  extern __shared__ char sm[];           // 131088: group g LDS bank at sm + g*65536; counters at 131072
  int t = threadIdx.x, lane = t & 63, wid = t >> 6, q4 = lane >> 4, l15 = lane & 15;
  int half = wid >> 2, wv = wid & 3;
  int fblk = blockIdx.x;
  int g = (fblk & 7) * 32 + (fblk >> 3); // XCD swizzle (256 = 8*32, bijective)
  int nb = g & 31, bh = g >> 5;
  int b = bh >> 1, hh = bh & 1;
  int n0 = nb * 128;
  char* smg = sm + half * 65536;
  int* cntg = (int*)(sm + 131072 + half * 8);
  if (wv == 0 && lane == 0) *cntg = 0;   // zero own group's counter (published by first __syncthreads)
  const char* Qg = (const char*)(Q + ((size_t)bh * 4096 + n0) * 128);
  const char* Kg = (const char*)(K + (size_t)bh * 4096 * 128) + half * 524288;
  const char* Vg = (const char*)(V + (size_t)bh * 128 * 4096) + half * 4096;
  // Q fragments direct from global (both groups read the SAME 128 q rows)
  f16x8 qf[2][4];
#pragma unroll
  for (int nt = 0; nt < 2; nt++)
#pragma unroll
    for (int kt = 0; kt < 4; kt++) {
      int rn = wv * 32 + nt * 16 + l15;
      qf[nt][kt] = *(const f16x8*)(Qg + (size_t)rn * 256 + kt * 64 + q4 * 16);
    }
  // loop-invariant per-lane DS read bases (hoisted swizzle algebra), group-local
  const char* pT0 = smg + (((l15 * 256 + 0 * 64 + q4 * 16) ^ (l15 << 4)));
  const char* pT1 = smg + (((l15 * 256 + 1 * 64 + q4 * 16) ^ (l15 << 4)));
  const char* pT2 = smg + (((l15 * 256 + 2 * 64 + q4 * 16) ^ (l15 << 4)));
  const char* pT3 = smg + (((l15 * 256 + 3 * 64 + q4 * 16) ^ (l15 << 4)));
  const char* pU0 = smg + 32768 + (((l15 * 128 + 0 * 64 + q4 * 16) ^ ((l15 & 7) << 4)));
  const char* pU1 = smg + 32768 + (((l15 * 128 + 1 * 64 + q4 * 16) ^ ((l15 & 7) << 4)));
  // loop-invariant staging offsets (4 chunks each for K and V, per group-wave wv)
  int ks[4], vs[4], lch[4];
#pragma unroll
  for (int c2 = 0; c2 < 4; c2++) {
    int ch = wv * 1024 + c2 * 4096;
    int o = ch + lane * 16;
    lch[c2] = ch;
    ks[c2] = o ^ (((o >> 8) & 15) << 4);
    int dd = o >> 7;
    vs[c2] = dd * 8192 + ((o & 127) ^ ((dd & 7) << 4));
  }
  f32x4 Ofr[8][2] = {};
  f32x4 sTa[4][2], sTb[4][2];
  float mrun[2] = {-3e38f, -3e38f};
  float lrun[2] = {0.f, 0.f};
  const f32x4 zf4 = {0.f, 0.f, 0.f, 0.f};

// group-local barrier: drain own staging, bump counter, spin until all 4 group waves passed.
#define GBAR(tgt)                                                                   \
  {                                                                                 \
    asm volatile("s_waitcnt vmcnt(0) lgkmcnt(0)" ::: "memory");                     \
    if (lane == 0) atomicAdd(cntg, 1);                                              \
    while (*((volatile int*)cntg) < (tgt)) __builtin_amdgcn_s_sleep(2);             \
    __builtin_amdgcn_sched_barrier(0);                                              \
    asm volatile("" ::: "memory");                                                  \
  }

  // prologue: stage K(0)->k0, V(0)->v0; full barrier (also publishes counter init)
#pragma unroll
  for (int c2 = 0; c2 < 4; c2++) gld_lds16(smg + lch[c2], Kg + ks[c2]);
#pragma unroll
  for (int c2 = 0; c2 < 4; c2++) gld_lds16(smg + 32768 + lch[c2], Vg + vs[c2]);
  asm volatile("s_waitcnt vmcnt(0)" ::: "memory");
  __syncthreads();
  // stage K(1)->k1 (in flight), compute QK(0) from k0 -> sTa, then group barrier (event 1)
  const char* kgp = Kg + 16384;
  const char* vgp = Vg;
#pragma unroll
  for (int c2 = 0; c2 < 4; c2++) gld_lds16(smg + 16384 + lch[c2], kgp + ks[c2]);
#pragma unroll
  for (int mt = 0; mt < 4; mt++)
#pragma unroll
    for (int nt = 0; nt < 2; nt++) sTa[mt][nt] = zf4;
#pragma unroll
  for (int kt = 0; kt < 4; kt++) {
    const char* pT = (kt == 0) ? pT0 : (kt == 1) ? pT1 : (kt == 2) ? pT2 : pT3;
    f16x8 kf[4];
#pragma unroll
    for (int mt = 0; mt < 4; mt++) kf[mt] = *(const f16x8*)(pT + mt * 4096);
#pragma unroll
    for (int mt = 0; mt < 4; mt++)
#pragma unroll
      for (int nt = 0; nt < 2; nt++)
        sTa[mt][nt] = __builtin_amdgcn_mfma_f32_16x16x32_f16(kf[mt], qf[nt][kt], sTa[mt][nt], 0, 0, 0);
  }
  GBAR(4);

// body i: stage K(i+2)->KSTG, stage V(i+1)->VSTG, QK(i+1) from KQK -> STNEXT,
//         softmax(i) on STPREV, PV(i) from VPV, group barrier.
#define ATTN_BODY(KSTG, VSTG, KQK, VPV, STPREV, STNEXT, doK, doV, doQK, tgt)        \
  {                                                                                 \
    if (doK) {                                                                      \
      kgp += 16384;                                                                 \
      _Pragma("unroll") for (int c2 = 0; c2 < 4; c2++)                              \
          gld_lds16(smg + (KSTG) + lch[c2], kgp + ks[c2]);                          \
    }                                                                               \
    if (doV) {                                                                      \
      vgp += 128;                                                                   \
      _Pragma("unroll") for (int c2 = 0; c2 < 4; c2++)                              \
          gld_lds16(smg + (VSTG) + lch[c2], vgp + vs[c2]);                          \
    }                                                                               \
    if (doQK) {                                                                     \
      _Pragma("unroll") for (int mt = 0; mt < 4; mt++)                              \
          _Pragma("unroll") for (int nt = 0; nt < 2; nt++) STNEXT[mt][nt] = zf4;    \
      _Pragma("unroll") for (int kt = 0; kt < 4; kt++) {                            \
        const char* pT = (kt == 0) ? pT0 : (kt == 1) ? pT1 : (kt == 2) ? pT2 : pT3; \
        f16x8 kf[4];                                                                \
        _Pragma("unroll") for (int mt = 0; mt < 4; mt++)                            \
            kf[mt] = *(const f16x8*)(pT + (KQK) + mt * 4096);                       \
        __builtin_amdgcn_s_setprio(1);                                              \
        _Pragma("unroll") for (int mt = 0; mt < 4; mt++)                            \
            _Pragma("unroll") for (int nt = 0; nt < 2; nt++)                        \
                STNEXT[mt][nt] = __builtin_amdgcn_mfma_f32_16x16x32_f16(            \
                    kf[mt], qf[nt][kt], STNEXT[mt][nt], 0, 0, 0);                   \
        __builtin_amdgcn_s_setprio(0);                                              \
      }                                                                             \
    }                                                                               \
    unsigned U[2][4][2];                                                            \
    _Pragma("unroll") for (int nt = 0; nt < 2; nt++) {                              \
      float mx = STPREV[0][nt][0];                                                  \
      _Pragma("unroll") for (int mt = 0; mt < 4; mt++)                              \
          _Pragma("unroll") for (int j = 0; j < 4; j++)                             \
              mx = fmaxf(mx, STPREV[mt][nt][j]);                                    \
      mx = fmaxf(mx, __shfl_xor(mx, 16));                                           \
      mx = fmaxf(mx, __shfl_xor(mx, 32));                                           \
      float mn = mrun[nt];                                                          \
      if (!__all(mx - mn <= 8.f)) {                                                 \
        mn = fmaxf(mrun[nt], mx);                                                   \
        float al = v_exp2(mrun[nt] - mn);                                           \
        mrun[nt] = mn;                                                              \
        lrun[nt] *= al;                                                             \
        _Pragma("unroll") for (int dt = 0; dt < 8; dt++) Ofr[dt][nt] *= al;         \
      }                                                                             \
      float rs = 0.f;                                                               \
      _Pragma("unroll") for (int mt = 0; mt < 4; mt++) {                            \
        float p0 = v_exp2(STPREV[mt][nt][0] - mn);                                  \
        float p1 = v_exp2(STPREV[mt][nt][1] - mn);                                  \
        float p2 = v_exp2(STPREV[mt][nt][2] - mn);                                  \
        float p3 = v_exp2(STPREV[mt][nt][3] - mn);                                  \
        rs += (p0 + p1) + (p2 + p3);                                                \
        U[nt][mt][0] = pk2h(p0, p1);                                                \
        U[nt][mt][1] = pk2h(p2, p3);                                                \
      }                                                                             \
      rs += __shfl_xor(rs, 16);                                                     \
      rs += __shfl_xor(rs, 32);                                                     \
      lrun[nt] += rs;                                                               \
    }                                                                               \
    _Pragma("unroll") for (int kt = 0; kt < 2; kt++) {                              \
      const char* pU = kt ? pU1 : pU0;                                              \
      f16x8 pf[2];                                                                  \
      _Pragma("unroll") for (int nt = 0; nt < 2; nt++) {                            \
        uint4 fr;                                                                   \
        fr.x = U[nt][2 * kt][0];                                                    \
        fr.y = U[nt][2 * kt][1];                                                    \
        fr.z = U[nt][2 * kt + 1][0];                                                \
        fr.w = U[nt][2 * kt + 1][1];                                                \
        pf[nt] = __builtin_bit_cast(f16x8, fr);                                     \
      }                                                                             \
      f16x8 vf[8];                                                                  \
      _Pragma("unroll") for (int dt = 0; dt < 8; dt++)                              \
          vf[dt] = *(const f16x8*)(pU + ((VPV)-32768) + dt * 2048);                 \
      __builtin_amdgcn_s_setprio(1);                                                \
      _Pragma("unroll") for (int dt = 0; dt < 8; dt++)                              \
          _Pragma("unroll") for (int nt = 0; nt < 2; nt++)                          \
              Ofr[dt][nt] = __builtin_amdgcn_mfma_f32_16x16x32_f16(                 \
                  vf[dt], pf[nt], Ofr[dt][nt], 0, 0, 0);                            \
      __builtin_amdgcn_s_setprio(0);                                                \
    }                                                                               \
    GBAR(tgt);                                                                      \
  }

  for (int it2 = 0; it2 < 16; it2++) {
    // even i = 2*it2: K(i+2)->buf0, V(i+1)->v1(49152), QK(i+1) from k1(16384), PV(i) from v0(32768)
    ATTN_BODY(0, 49152, 16384, 32768, sTa, sTb, (it2 < 15), true, true, 8 + 8 * it2);
    // odd i = 2*it2+1: K(i+2)->buf1, V(i+1)->v0(32768), QK(i+1) from k0(0), PV(i) from v1(49152)
    ATTN_BODY(16384, 32768, 0, 49152, sTb, sTa, (it2 < 15), (it2 < 15), (it2 < 15), 12 + 8 * it2);
  }
#undef ATTN_BODY
#undef GBAR

  // full barrier: group 1 writes xch into group 0's (now dead) staging LDS
  __syncthreads();
  float* xch = (float*)sm;               // [64 regs][256 slots] f32 = 64KB
  float* mlx = (float*)(sm + 65536);     // [4][256] f32
  int slot = t & 255;
  if (half == 1) {
#pragma unroll
    for (int dt = 0; dt < 8; dt++)
#pragma unroll
      for (int nt = 0; nt < 2; nt++)
#pragma unroll
        for (int j = 0; j < 4; j++)
          xch[(dt * 8 + nt * 4 + j) * 256 + slot] = Ofr[dt][nt][j];
    mlx[slot] = mrun[0];
    mlx[256 + slot] = mrun[1];
    mlx[512 + slot] = lrun[0];
    mlx[768 + slot] = lrun[1];
  }
  __syncthreads();
  if (half == 0) {
    float m1[2] = {mlx[slot], mlx[256 + slot]};
    float l1[2] = {mlx[512 + slot], mlx[768 + slot]};
    float a0[2], a1[2], li[2];
#pragma unroll
    for (int nt = 0; nt < 2; nt++) {
      float ms = fmaxf(mrun[nt], m1[nt]);
      a0[nt] = v_exp2(mrun[nt] - ms);
      a1[nt] = v_exp2(m1[nt] - ms);
      li[nt] = v_rcp(lrun[nt] * a0[nt] + l1[nt] * a1[nt]);
    }
    float* og = out + (size_t)(b * 256 + hh * 128) * 4096 + n0 + wv * 32;
#pragma unroll
    for (int dt = 0; dt < 8; dt++)
#pragma unroll
      for (int nt = 0; nt < 2; nt++)
#pragma unroll
        for (int j = 0; j < 4; j++) {
          int dd = dt * 16 + q4 * 4 + j;
          float o1v = xch[(dt * 8 + nt * 4 + j) * 256 + slot];
          og[(size_t)dd * 4096 + nt * 16 + l15] =
              (Ofr[dt][nt][j] * a0[nt] + o1v * a1[nt]) * li[nt];
        }
  }
}

extern "C" void kernel_launch(void* const* d_in, const int* in_sizes, int n_in,
                              void* d_out, int out_size, void* d_ws, size_t ws_size,
                              hipStream_t stream) {
  (void)in_sizes; (void)n_in; (void)out_size;
  const float* x  = (const float*)d_in[0];
  const float* qw = (const float*)d_in[1];
  const float* qb = (const float*)d_in[2];
  const float* kw = (const float*)d_in[3];
  const float* kb = (const float*)d_in[4];
  const float* vw = (const float*)d_in[5];
  const float* vb = (const float*)d_in[6];
  char* ws = (char*)d_ws;
  if (ws_size < 37822464) return;
  char* xpad = ws;
  unsigned short* Wq = (unsigned short*)(ws + 11214848);
  unsigned short* Wk = (unsigned short*)(ws + 12394496);
  unsigned short* Wv = (unsigned short*)(ws + 12525568);
  unsigned short* Qb = (unsigned short*)(ws + 12656640);
  unsigned short* Kb = (unsigned short*)(ws + 21045248);
  unsigned short* Vb = (unsigned short*)(ws + 29433856);
  k_prep_x<<<dim3(64, 4), dim3(256), 0, stream>>>(x, xpad, qw, kw, vw, Wq, Wk, Wv);
  k_conv_kv<<<dim3(128, 2, 2), dim3(256), 0, stream>>>(xpad, Wk, Wv, kb, vb, Kb, Vb);
  k_conv_q<<<dim3(256), dim3(512), 146432, stream>>>(xpad, Wq, qb, Qb);
  k_attn<<<dim3(256), dim3(512), 131088, stream>>>(Qb, Kb, Vb, (float*)d_out);
}

// Round 18
// 154.545 us; speedup vs baseline: 1.0516x; 1.0516x over previous
//
#include <hip/hip_runtime.h>
#include <cstdint>

typedef __attribute__((ext_vector_type(8))) _Float16 f16x8;
typedef __attribute__((ext_vector_type(4))) float f32x4;

#define DEV static __device__ __forceinline__

DEV void gld_lds16(void* lds_base, const void* gsrc) {
  __builtin_amdgcn_global_load_lds(
      (const __attribute__((address_space(1))) unsigned int*)gsrc,
      (__attribute__((address_space(3))) unsigned int*)lds_base,
      16, 0, 0);
}
DEV unsigned short f2h(float f) {
  _Float16 h = (_Float16)f;
  return __builtin_bit_cast(unsigned short, h);
}
DEV unsigned pk2h(float a, float b) {
  auto h2 = __builtin_amdgcn_cvt_pkrtz(a, b);
  return __builtin_bit_cast(unsigned, h2);
}
DEV float v_exp2(float x) { float r; asm("v_exp_f32 %0, %1" : "=v"(r) : "v"(x)); return r; }
DEV float v_rcp(float x) { float r; asm("v_rcp_f32 %0, %1" : "=v"(r) : "v"(x)); return r; }

// ---------------- geometry ----------------
// B=4, C=256, H=W=64, N=4096, heads=2, hd=128
// ws layout (bytes):
//   Xpad [4][74][74][256] f16 : 0        .. 11214848
//   Wq [3][3][256][256] f16   : 11214848 .. 12394496
//   Wk [256][256] f16         : 12394496 .. 12525568
//   Wv [256][256] f16         : 12525568 .. 12656640
//   Q  [8][4096][128] f16     : 12656640 .. 21045248   (pre-scaled by log2e/sqrt(128))
//   K  [8][4096][128] f16     : 21045248 .. 29433856
//   V  [8][128][4096] f16     : 29433856 .. 37822464   (m-permuted per 64-block: s=[m5,m3,m2,m4,m1,m0])

// ---------- prep: x -> Xpad (f16, pixel-major, halo 5) + halo zeroing + weights -> f16 ----------
__global__ __launch_bounds__(256) void k_prep_x(
    const float* __restrict__ x, char* __restrict__ xpad,
    const float* __restrict__ qw, const float* __restrict__ kw, const float* __restrict__ vw,
    unsigned short* __restrict__ Wq, unsigned short* __restrict__ Wk, unsigned short* __restrict__ Wv) {
  __shared__ float xs[32 * 257];
  int h = blockIdx.x, b = blockIdx.y, t = threadIdx.x;
  // fused weight conversion (one gid per thread; 256 blocks x 256 threads cover 65536)
  int gid = (b * 64 + h) * 256 + t;
  const float* q9 = qw + (size_t)gid * 9;
#pragma unroll
  for (int tp = 0; tp < 9; tp++) Wq[tp * 65536 + gid] = f2h(q9[tp]);
  Wk[gid] = f2h(kw[gid]);
  Wv[gid] = f2h(vw[gid]);
  // halo zeroing (replaces the 11MB memset): disjoint from all data writes
  uint4 z = {0, 0, 0, 0};
  char* rowbase = xpad + ((size_t)(b * 74 + h + 5) * 74) * 512;
  for (int i = t; i < 320; i += 256) {              // col halo of this data row
    int col = i >> 5, off = (i & 31) * 16;
    int w = (col < 5) ? col : 64 + col;             // cols 0-4, 69-73
    *(uint4*)(rowbase + (size_t)w * 512 + off) = z;
  }
  if (h < 10) {                                     // full halo rows 0-4, 69-73
    int r = (h < 5) ? h : 64 + h;
    char* rb = xpad + ((size_t)(b * 74 + r) * 74) * 512;
    for (int i = t; i < 2368; i += 256) *(uint4*)(rb + (size_t)i * 16) = z;
  }
  const float* xb = x + (size_t)b * 1048576 + h * 64;
  for (int half = 0; half < 2; half++) {
    int w0 = half * 32;
    for (int kk = 0; kk < 32; kk++) {
      int flat = kk * 256 + t;       // ci*32 + w
      int ci = flat >> 5, w = flat & 31;
      xs[w * 257 + ci] = xb[ci * 4096 + w0 + w];
    }
    __syncthreads();
    for (int g = 0; g < 4; g++) {
      int w = g * 8 + (t >> 5);
      int cg = t & 31;               // 8-ci chunk
      float v0 = xs[w * 257 + cg * 8 + 0], v1 = xs[w * 257 + cg * 8 + 1];
      float v2 = xs[w * 257 + cg * 8 + 2], v3 = xs[w * 257 + cg * 8 + 3];
      float v4 = xs[w * 257 + cg * 8 + 4], v5 = xs[w * 257 + cg * 8 + 5];
      float v6 = xs[w * 257 + cg * 8 + 6], v7 = xs[w * 257 + cg * 8 + 7];
      uint4 pk;
      pk.x = pk2h(v0, v1);
      pk.y = pk2h(v2, v3);
      pk.z = pk2h(v4, v5);
      pk.w = pk2h(v6, v7);
      *(uint4*)(xpad + ((size_t)((b * 74 + h + 5) * 74) + w0 + w + 5) * 512 + cg * 16) = pk;
    }
    __syncthreads();
  }
}

// ---------- 1x1 convs: K[bh][m][d], V[bh][d][s(m)] ----------
// c-loop double-buffered: X/W ping-pong (64KB LDS), staging hidden under compute.
__global__ __launch_bounds__(256, 2) void k_conv_kv(
    const char* __restrict__ xpad, const unsigned short* __restrict__ Wk,
    const unsigned short* __restrict__ Wv, const float* __restrict__ kb,
    const float* __restrict__ vb, unsigned short* __restrict__ K, unsigned short* __restrict__ V) {
  __shared__ char sm[65536];   // buf0: X@0 W@16384 ; buf1: X@32768 W@49152
  int t = threadIdx.x, lane = t & 63, wid = t >> 6, q4 = lane >> 4, l15 = lane & 15;
  int px0 = blockIdx.x * 128;
  int b = px0 >> 12, nn = px0 & 4095;
  int h = blockIdx.y;          // co half / head
  int mode = blockIdx.z;       // 0: K (D[px][co]),  1: V (D[co][px])
  int co0 = h * 128;
  const char* Wsrc = (const char*)(mode ? Wv : Wk);
  int wm = wid & 1, wn = wid >> 1;

#define STAGE_KV(base_, c_)                                                       \
  {                                                                               \
    for (int ch = wid * 1024; ch < 16384; ch += 4096) {                           \
      int o = ch + lane * 16;                                                     \
      int r = o >> 7;                                                             \
      int n = nn + r, hh = n >> 6, ww2 = n & 63;                                  \
      int col = (o & 127) ^ ((r & 7) << 4);                                       \
      gld_lds16((base_) + ch,                                                     \
                xpad + ((size_t)((b * 74 + hh + 5) * 74) + ww2 + 5) * 512 + (c_)*128 + col); \
    }                                                                             \
    for (int ch = wid * 1024; ch < 16384; ch += 4096) {                           \
      int o = ch + lane * 16;                                                     \
      int r = o >> 7;                                                             \
      int col = (o & 127) ^ ((r & 7) << 4);                                       \
      gld_lds16((base_) + 16384 + ch, Wsrc + (co0 + r) * 512 + (c_)*128 + col);   \
    }                                                                             \
  }

  STAGE_KV(sm, 0);
  asm volatile("s_waitcnt vmcnt(0)" ::: "memory");
  __syncthreads();

  f32x4 acc[4][4] = {};
  for (int c = 0; c < 4; c++) {
    char* cb = sm + (c & 1) * 32768;
    if (c < 3) STAGE_KV(sm + ((c & 1) ^ 1) * 32768, c + 1);
    const char* Xs = cb;
    const char* Ws = cb + 16384;
    int xg = mode ? wn : wm;   // X-frag 64-row group
    int wg = mode ? wm : wn;   // W-frag 64-row group
#pragma unroll
    for (int kt = 0; kt < 2; kt++) {
      f16x8 xf[4], wf[4];
#pragma unroll
      for (int i = 0; i < 4; i++) {
        int rx = xg * 64 + i * 16 + l15;
        xf[i] = *(const f16x8*)(Xs + ((rx * 128 + kt * 64 + q4 * 16) ^ ((rx & 7) << 4)));
        int rw = wg * 64 + i * 16 + l15;
        wf[i] = *(const f16x8*)(Ws + ((rw * 128 + kt * 64 + q4 * 16) ^ ((rw & 7) << 4)));
      }
#pragma unroll
      for (int m = 0; m < 4; m++)
#pragma unroll
        for (int n = 0; n < 4; n++)
          acc[m][n] = mode ? __builtin_amdgcn_mfma_f32_16x16x32_f16(wf[m], xf[n], acc[m][n], 0, 0, 0)
                           : __builtin_amdgcn_mfma_f32_16x16x32_f16(xf[m], wf[n], acc[m][n], 0, 0, 0);
    }
    asm volatile("s_waitcnt vmcnt(0)" ::: "memory");
    __syncthreads();
  }
#undef STAGE_KV
  int bh = b * 2 + h;
  if (mode == 0) {
#pragma unroll
    for (int m = 0; m < 4; m++)
#pragma unroll
      for (int n = 0; n < 4; n++) {
        int dd = wn * 64 + n * 16 + l15;
        float bias = kb[co0 + dd];
#pragma unroll
        for (int j = 0; j < 4; j++) {
          int npix = nn + wm * 64 + m * 16 + q4 * 4 + j;
          K[(size_t)(bh * 4096 + npix) * 128 + dd] = f2h(acc[m][n][j] + bias);
        }
      }
  } else {
#pragma unroll
    for (int m = 0; m < 4; m++)
#pragma unroll
      for (int j = 0; j < 4; j++) {
        int cr = wm * 64 + m * 16 + q4 * 4 + j;
        float bias = vb[co0 + cr];
#pragma unroll
        for (int n = 0; n < 4; n++) {
          // m-permuted storage within each 64-block: m_local = n*16 + l15
          // -> s = (n>>1)*32 + (l15>>2)*8 + (n&1)*4 + (l15&3)
          int pc = nn + wn * 64 + (n >> 1) * 32 + (l15 >> 2) * 8 + (n & 1) * 4 + (l15 & 3);
          V[(size_t)(bh * 128 + cr) * 4096 + pc] = f2h(acc[m][n][j] + bias);
        }
      }
  }
}

// ---------- dilated 3x3 conv sum(SiLU) -> Q[bh][n][d] ----------
// 512-thread blocks (8 waves), 128 px (2 h-rows) per block, grid 256 (XCD-swizzled), 1 block/CU.
// Bs double-buffered at kw granularity AND As double-buffered per (kh,c).
__global__ __launch_bounds__(512, 2) void k_conv_q(
    const char* __restrict__ xpad, const unsigned short* __restrict__ Wq,
    const float* __restrict__ qb, unsigned short* __restrict__ Q) {
  extern __shared__ char sm[];
  int t = threadIdx.x, lane = t & 63, wid = t >> 6, q4 = lane >> 4, l15 = lane & 15;
  int fblk = blockIdx.x;
  int g = (fblk & 7) * 32 + (fblk >> 3);       // XCD x owns one (b,ch2) combo
  int h2 = g & 31, b = (g >> 5) & 3, ch2 = g >> 7;
  int h0 = h2 * 2;
  int co0 = ch2 * 128;
  int wn = wid & 1, wq = wid >> 1;
  int hr = wq >> 1, wloc = wq & 1;
  const int dil[3] = {1, 3, 5};
  const char* WqB = (const char*)Wq;
  f32x4 accd[3][2][4] = {};

#define STAGE_B(dstbuf, kh_, c_, kw_)                                             \
  {                                                                               \
    const char* src_ = WqB + (size_t)((kh_)*3 + (kw_)) * 131072 + co0 * 512 + (c_)*128; \
    char* dst_ = (dstbuf);                                                        \
    for (int ch = wid * 1024; ch < 16384; ch += 8192) {                           \
      int o = ch + lane * 16;                                                     \
      int r = o >> 7;                                                             \
      int col = (o & 127) ^ ((r & 7) << 4);                                       \
      gld_lds16(dst_ + ch, src_ + r * 512 + col);                                 \
    }                                                                             \
  }

#define STAGE_A_ROW(abase_, slot_, pr_, c_)                                       \
  {                                                                               \
    const char* src_ = xpad + ((size_t)(b * 74 + (pr_)) * 74) * 512 + (c_)*128;   \
    char* dst_ = (abase_) + (slot_)*9472;                                         \
    for (int ch = wid * 1024; ch < 9472; ch += 8192) {                            \
      int o = ch + lane * 16;                                                     \
      if (o < 9472) {                                                             \
        int r = o >> 7;                                                           \
        int col = (o & 127) ^ ((r & 7) << 4);                                     \
        gld_lds16(dst_ + ch, src_ + r * 512 + col);                               \
      }                                                                           \
    }                                                                             \
  }

#define STAGE_A(abase_, kh_, c_)                                                  \
  {                                                                               \
    if ((kh_) == 1) {                                                             \
      for (int s = 0; s < 2; s++) STAGE_A_ROW(abase_, s, h0 + s + 5, c_);         \
    } else {                                                                      \
      for (int di = 0; di < 3; di++)                                              \
        for (int s = 0; s < 2; s++)                                               \
          STAGE_A_ROW(abase_, di * 2 + s, h0 + s + ((kh_)-1) * dil[di] + 5, c_);  \
    }                                                                             \
  }

  // prologue
  STAGE_A(sm + 32768, 0, 0);
  STAGE_B(sm, 0, 0, 0);
  asm volatile("s_waitcnt vmcnt(0)" ::: "memory");
  __syncthreads();

  int curB = 0, curA = 0;
  for (int kh = 0; kh < 3; kh++) {
    for (int c = 0; c < 4; c++) {
      // next (kh,c) for the As prefetch
      int cn2 = c + 1, khn2 = kh;
      if (cn2 == 4) { cn2 = 0; khn2 = kh + 1; }
      for (int kw = 0; kw < 3; kw++) {
        // prefetch next unit's weights
        int kwn = kw + 1, cn = c, khn = kh;
        if (kwn == 3) { kwn = 0; cn = c + 1; if (cn == 4) { cn = 0; khn = kh + 1; } }
        char* Bnext = curB ? sm : sm + 16384;
        if (khn < 3) STAGE_B(Bnext, khn, cn, kwn);
        // prefetch next (kh,c)'s As during the kw==0 unit
        if (kw == 0 && khn2 < 3) STAGE_A(sm + 32768 + (curA ^ 1) * 56832, khn2, cn2);
        // compute unit (kh, c, kw)
        const char* Bc = curB ? sm + 16384 : sm;
        const char* Abase = sm + 32768 + curA * 56832;
        f16x8 bf[4][2];
#pragma unroll
        for (int n = 0; n < 4; n++)
#pragma unroll
          for (int kt = 0; kt < 2; kt++) {
            int rc = wn * 64 + n * 16 + l15;
            bf[n][kt] = *(const f16x8*)(Bc + ((rc * 128 + kt * 64 + q4 * 16) ^ ((rc & 7) << 4)));
          }
#pragma unroll
        for (int di = 0; di < 3; di++) {
          int dw = (kw - 1) * dil[di] + 5;
          const char* Ad = Abase + (kh == 1 ? hr : di * 2 + hr) * 9472;
          f16x8 af[2][2];
#pragma unroll
          for (int m = 0; m < 2; m++)
#pragma unroll
            for (int kt = 0; kt < 2; kt++) {
              int wp = wloc * 32 + m * 16 + l15 + dw;    // [0,73]
              af[m][kt] = *(const f16x8*)(Ad + ((wp * 128 + kt * 64 + q4 * 16) ^ ((wp & 7) << 4)));
            }
          __builtin_amdgcn_s_setprio(1);
#pragma unroll
          for (int m = 0; m < 2; m++)
#pragma unroll
            for (int n = 0; n < 4; n++)
#pragma unroll
              for (int kt = 0; kt < 2; kt++)
                accd[di][m][n] = __builtin_amdgcn_mfma_f32_16x16x32_f16(af[m][kt], bf[n][kt], accd[di][m][n], 0, 0, 0);
          __builtin_amdgcn_s_setprio(0);
        }
        asm volatile("s_waitcnt vmcnt(0)" ::: "memory");  // drain prefetches
        __syncthreads();
        curB ^= 1;
      }
      if (khn2 < 3) curA ^= 1;   // flip As at (kh,c) boundary when a prefetch was issued
    }
  }
#undef STAGE_A
#undef STAGE_A_ROW
#undef STAGE_B
  const float LOG2E = 1.4426950408889634f;
  const float QSCALE = 0.12751879523176862f;  // log2e / sqrt(128)
#pragma unroll
  for (int n = 0; n < 4; n++) {
    float bias = qb[co0 + wn * 64 + n * 16 + l15];
#pragma unroll
    for (int m = 0; m < 2; m++)
#pragma unroll
      for (int j = 0; j < 4; j++) {
        float s = 0.f;
#pragma unroll
        for (int di = 0; di < 3; di++) {
          float v = accd[di][m][n][j] + bias;
          s += v * v_rcp(1.0f + v_exp2(-v * LOG2E));     // SiLU
        }
        int w = wloc * 32 + m * 16 + q4 * 4 + j;
        int npix = (h0 + hr) * 64 + w;
        int dd = wn * 64 + n * 16 + l15;
        Q[((size_t)(b * 2 + ch2) * 4096 + npix) * 128 + dd] = f2h(s * QSCALE);
      }
  }
}

// ---------- flash attention, fused halves + softmax pipeline: grid 256, 512 thr, 1 block/CU ----
// R16-exact (proven best, 89.2us). Two independent 4-wave groups (group = wid>>2) each process
// one KV half in their own 64KB LDS bank; one-tile pipeline skew (QK(i+1) alongside softmax(i));
// block-wide barriers. End: group 1 publishes (m,l,O) via LDS, group 0 merges + writes output.
__global__ __launch_bounds__(512) void k_attn(
    const unsigned short* __restrict__ Q, const unsigned short* __restrict__ K,
    const unsigned short* __restrict__ V, float* __restrict__ out) {
  extern __shared__ char sm[];           // 131072: group g at sm + g*65536
  int t = threadIdx.x, lane = t & 63, wid = t >> 6, q4 = lane >> 4, l15 = lane & 15;
  int half = wid >> 2, wv = wid & 3;
  int fblk = blockIdx.x;
  int g = (fblk & 7) * 32 + (fblk >> 3); // XCD swizzle (256 = 8*32, bijective)
  int nb = g & 31, bh = g >> 5;
  int b = bh >> 1, hh = bh & 1;
  int n0 = nb * 128;
  char* smg = sm + half * 65536;
  const char* Qg = (const char*)(Q + ((size_t)bh * 4096 + n0) * 128);
  const char* Kg = (const char*)(K + (size_t)bh * 4096 * 128) + half * 524288;
  const char* Vg = (const char*)(V + (size_t)bh * 128 * 4096) + half * 4096;
  // Q fragments direct from global (both groups read the SAME 128 q rows)
  f16x8 qf[2][4];
#pragma unroll
  for (int nt = 0; nt < 2; nt++)
#pragma unroll
    for (int kt = 0; kt < 4; kt++) {
      int rn = wv * 32 + nt * 16 + l15;
      qf[nt][kt] = *(const f16x8*)(Qg + (size_t)rn * 256 + kt * 64 + q4 * 16);
    }
  // loop-invariant per-lane DS read bases (hoisted swizzle algebra), group-local
  const char* pT0 = smg + (((l15 * 256 + 0 * 64 + q4 * 16) ^ (l15 << 4)));
  const char* pT1 = smg + (((l15 * 256 + 1 * 64 + q4 * 16) ^ (l15 << 4)));
  const char* pT2 = smg + (((l15 * 256 + 2 * 64 + q4 * 16) ^ (l15 << 4)));
  const char* pT3 = smg + (((l15 * 256 + 3 * 64 + q4 * 16) ^ (l15 << 4)));
  const char* pU0 = smg + 32768 + (((l15 * 128 + 0 * 64 + q4 * 16) ^ ((l15 & 7) << 4)));
  const char* pU1 = smg + 32768 + (((l15 * 128 + 1 * 64 + q4 * 16) ^ ((l15 & 7) << 4)));
  // loop-invariant staging offsets (4 chunks each for K and V, per group-wave wv)
  int ks[4], vs[4], lch[4];
#pragma unroll
  for (int c2 = 0; c2 < 4; c2++) {
    int ch = wv * 1024 + c2 * 4096;
    int o = ch + lane * 16;
    lch[c2] = ch;
    ks[c2] = o ^ (((o >> 8) & 15) << 4);
    int dd = o >> 7;
    vs[c2] = dd * 8192 + ((o & 127) ^ ((dd & 7) << 4));
  }
  f32x4 Ofr[8][2] = {};
  f32x4 sTa[4][2], sTb[4][2];
  float mrun[2] = {-3e38f, -3e38f};
  float lrun[2] = {0.f, 0.f};
  const f32x4 zf4 = {0.f, 0.f, 0.f, 0.f};

  // prologue: stage K(0)->k0, V(0)->v0; drain; barrier
#pragma unroll
  for (int c2 = 0; c2 < 4; c2++) gld_lds16(smg + lch[c2], Kg + ks[c2]);
#pragma unroll
  for (int c2 = 0; c2 < 4; c2++) gld_lds16(smg + 32768 + lch[c2], Vg + vs[c2]);
  asm volatile("s_waitcnt vmcnt(0)" ::: "memory");
  __syncthreads();
  // stage K(1)->k1 (in flight), compute QK(0) from k0 -> sTa, then barrier
  const char* kgp = Kg + 16384;
  const char* vgp = Vg;
#pragma unroll
  for (int c2 = 0; c2 < 4; c2++) gld_lds16(smg + 16384 + lch[c2], kgp + ks[c2]);
#pragma unroll
  for (int mt = 0; mt < 4; mt++)
#pragma unroll
    for (int nt = 0; nt < 2; nt++) sTa[mt][nt] = zf4;
#pragma unroll
  for (int kt = 0; kt < 4; kt++) {
    const char* pT = (kt == 0) ? pT0 : (kt == 1) ? pT1 : (kt == 2) ? pT2 : pT3;
    f16x8 kf[4];
#pragma unroll
    for (int mt = 0; mt < 4; mt++) kf[mt] = *(const f16x8*)(pT + mt * 4096);
#pragma unroll
    for (int mt = 0; mt < 4; mt++)
#pragma unroll
      for (int nt = 0; nt < 2; nt++)
        sTa[mt][nt] = __builtin_amdgcn_mfma_f32_16x16x32_f16(kf[mt], qf[nt][kt], sTa[mt][nt], 0, 0, 0);
  }
  __syncthreads();

// body i: stage K(i+2)->KSTG, stage V(i+1)->VSTG, QK(i+1) from KQK -> STNEXT,
//         softmax(i) on STPREV, PV(i) from VPV, barrier.
#define ATTN_BODY(KSTG, VSTG, KQK, VPV, STPREV, STNEXT, doK, doV, doQK)             \
  {                                                                                 \
    if (doK) {                                                                      \
      kgp += 16384;                                                                 \
      _Pragma("unroll") for (int c2 = 0; c2 < 4; c2++)                              \
          gld_lds16(smg + (KSTG) + lch[c2], kgp + ks[c2]);                          \
    }                                                                               \
    if (doV) {                                                                      \
      vgp += 128;                                                                   \
      _Pragma("unroll") for (int c2 = 0; c2 < 4; c2++)                              \
          gld_lds16(smg + (VSTG) + lch[c2], vgp + vs[c2]);                          \
    }                                                                               \
    if (doQK) {                                                                     \
      _Pragma("unroll") for (int mt = 0; mt < 4; mt++)                              \
          _Pragma("unroll") for (int nt = 0; nt < 2; nt++) STNEXT[mt][nt] = zf4;    \
      _Pragma("unroll") for (int kt = 0; kt < 4; kt++) {                            \
        const char* pT = (kt == 0) ? pT0 : (kt == 1) ? pT1 : (kt == 2) ? pT2 : pT3; \
        f16x8 kf[4];                                                                \
        _Pragma("unroll") for (int mt = 0; mt < 4; mt++)                            \
            kf[mt] = *(const f16x8*)(pT + (KQK) + mt * 4096);                       \
        __builtin_amdgcn_s_setprio(1);                                              \
        _Pragma("unroll") for (int mt = 0; mt < 4; mt++)                            \
            _Pragma("unroll") for (int nt = 0; nt < 2; nt++)                        \
                STNEXT[mt][nt] = __builtin_amdgcn_mfma_f32_16x16x32_f16(            \
                    kf[mt], qf[nt][kt], STNEXT[mt][nt], 0, 0, 0);                   \
        __builtin_amdgcn_s_setprio(0);                                              \
      }                                                                             \
    }                                                                               \
    unsigned U[2][4][2];                                                            \
    _Pragma("unroll") for (int nt = 0; nt < 2; nt++) {                              \
      float mx = STPREV[0][nt][0];                                                  \
      _Pragma("unroll") for (int mt = 0; mt < 4; mt++)                              \
          _Pragma("unroll") for (int j = 0; j < 4; j++)                             \
              mx = fmaxf(mx, STPREV[mt][nt][j]);                                    \
      mx = fmaxf(mx, __shfl_xor(mx, 16));                                           \
      mx = fmaxf(mx, __shfl_xor(mx, 32));                                           \
      float mn = mrun[nt];                                                          \
      if (!__all(mx - mn <= 8.f)) {                                                 \
        mn = fmaxf(mrun[nt], mx);                                                   \
        float al = v_exp2(mrun[nt] - mn);                                           \
        mrun[nt] = mn;                                                              \
        lrun[nt] *= al;                                                             \
        _Pragma("unroll") for (int dt = 0; dt < 8; dt++) Ofr[dt][nt] *= al;         \
      }                                                                             \
      float rs = 0.f;                                                               \
      _Pragma("unroll") for (int mt = 0; mt < 4; mt++) {                            \
        float p0 = v_exp2(STPREV[mt][nt][0] - mn);                                  \
        float p1 = v_exp2(STPREV[mt][nt][1] - mn);                                  \
        float p2 = v_exp2(STPREV[mt][nt][2] - mn);                                  \
        float p3 = v_exp2(STPREV[mt][nt][3] - mn);                                  \
        rs += (p0 + p1) + (p2 + p3);                                                \
        U[nt][mt][0] = pk2h(p0, p1);                                                \
        U[nt][mt][1] = pk2h(p2, p3);                                                \
      }                                                                             \
      rs += __shfl_xor(rs, 16);                                                     \
      rs += __shfl_xor(rs, 32);                                                     \
      lrun[nt] += rs;                                                               \
    }                                                                               \
    _Pragma("unroll") for (int kt = 0; kt < 2; kt++) {                              \
      const char* pU = kt ? pU1 : pU0;                                              \
      f16x8 pf[2];                                                                  \
      _Pragma("unroll") for (int nt = 0; nt < 2; nt++) {                            \
        uint4 fr;                                                                   \
        fr.x = U[nt][2 * kt][0];                                                    \
        fr.y = U[nt][2 * kt][1];                                                    \
        fr.z = U[nt][2 * kt + 1][0];                                                \
        fr.w = U[nt][2 * kt + 1][1];                                                \
        pf[nt] = __builtin_bit_cast(f16x8, fr);                                     \
      }                                                                             \
      f16x8 vf[8];                                                                  \
      _Pragma("unroll") for (int dt = 0; dt < 8; dt++)                              \
          vf[dt] = *(const f16x8*)(pU + ((VPV)-32768) + dt * 2048);                 \
      __builtin_amdgcn_s_setprio(1);                                                \
      _Pragma("unroll") for (int dt = 0; dt < 8; dt++)                              \
          _Pragma("unroll") for (int nt = 0; nt < 2; nt++)                          \
              Ofr[dt][nt] = __builtin_amdgcn_mfma_f32_16x16x32_f16(                 \
                  vf[dt], pf[nt], Ofr[dt][nt], 0, 0, 0);                            \
      __builtin_amdgcn_s_setprio(0);                                                \
    }                                                                               \
    __syncthreads();                                                                \
  }

  for (int it2 = 0; it2 < 16; it2++) {
    // even i = 2*it2: K(i+2)->buf0, V(i+1)->v1(49152), QK(i+1) from k1(16384), PV(i) from v0(32768)
    ATTN_BODY(0, 49152, 16384, 32768, sTa, sTb, (it2 < 15), true, true);
    // odd i = 2*it2+1: K(i+2)->buf1, V(i+1)->v0(32768), QK(i+1) from k0(0), PV(i) from v1(49152)
    ATTN_BODY(16384, 32768, 0, 49152, sTb, sTa, (it2 < 15), (it2 < 15), (it2 < 15));
  }
#undef ATTN_BODY

  // merge the two KV-half groups via LDS (staging buffers are dead now)
  float* xch = (float*)sm;               // [64 regs][256 slots] f32 = 64KB
  float* mlx = (float*)(sm + 65536);     // [4][256] f32
  int slot = t & 255;
  if (half == 1) {
#pragma unroll
    for (int dt = 0; dt < 8; dt++)
#pragma unroll
      for (int nt = 0; nt < 2; nt++)
#pragma unroll
        for (int j = 0; j < 4; j++)
          xch[(dt * 8 + nt * 4 + j) * 256 + slot] = Ofr[dt][nt][j];
    mlx[slot] = mrun[0];
    mlx[256 + slot] = mrun[1];
    mlx[512 + slot] = lrun[0];
    mlx[768 + slot] = lrun[1];
  }
  __syncthreads();
  if (half == 0) {
    float m1[2] = {mlx[slot], mlx[256 + slot]};
    float l1[2] = {mlx[512 + slot], mlx[768 + slot]};
    float a0[2], a1[2], li[2];
#pragma unroll
    for (int nt = 0; nt < 2; nt++) {
      float ms = fmaxf(mrun[nt], m1[nt]);
      a0[nt] = v_exp2(mrun[nt] - ms);
      a1[nt] = v_exp2(m1[nt] - ms);
      li[nt] = v_rcp(lrun[nt] * a0[nt] + l1[nt] * a1[nt]);
    }
    float* og = out + (size_t)(b * 256 + hh * 128) * 4096 + n0 + wv * 32;
#pragma unroll
    for (int dt = 0; dt < 8; dt++)
#pragma unroll
      for (int nt = 0; nt < 2; nt++)
#pragma unroll
        for (int j = 0; j < 4; j++) {
          int dd = dt * 16 + q4 * 4 + j;
          float o1v = xch[(dt * 8 + nt * 4 + j) * 256 + slot];
          og[(size_t)dd * 4096 + nt * 16 + l15] =
              (Ofr[dt][nt][j] * a0[nt] + o1v * a1[nt]) * li[nt];
        }
  }
}

extern "C" void kernel_launch(void* const* d_in, const int* in_sizes, int n_in,
                              void* d_out, int out_size, void* d_ws, size_t ws_size,
                              hipStream_t stream) {
  (void)in_sizes; (void)n_in; (void)out_size;
  const float* x  = (const float*)d_in[0];
  const float* qw = (const float*)d_in[1];
  const float* qb = (const float*)d_in[2];
  const float* kw = (const float*)d_in[3];
  const float* kb = (const float*)d_in[4];
  const float* vw = (const float*)d_in[5];
  const float* vb = (const float*)d_in[6];
  char* ws = (char*)d_ws;
  if (ws_size < 37822464) return;
  char* xpad = ws;
  unsigned short* Wq = (unsigned short*)(ws + 11214848);
  unsigned short* Wk = (unsigned short*)(ws + 12394496);
  unsigned short* Wv = (unsigned short*)(ws + 12525568);
  unsigned short* Qb = (unsigned short*)(ws + 12656640);
  unsigned short* Kb = (unsigned short*)(ws + 21045248);
  unsigned short* Vb = (unsigned short*)(ws + 29433856);
  k_prep_x<<<dim3(64, 4), dim3(256), 0, stream>>>(x, xpad, qw, kw, vw, Wq, Wk, Wv);
  k_conv_kv<<<dim3(128, 2, 2), dim3(256), 0, stream>>>(xpad, Wk, Wv, kb, vb, Kb, Vb);
  k_conv_q<<<dim3(256), dim3(512), 146432, stream>>>(xpad, Wq, qb, Qb);
  k_attn<<<dim3(256), dim3(512), 131072, stream>>>(Qb, Kb, Vb, (float*)d_out);
}